// Round 6
// baseline (66.489 us; speedup 1.0000x reference)
//
#include <hip/hip_runtime.h>

// Problem constants (fixed shapes from setup_inputs)
constexpr int KK = 3;
constexpr int K2 = 9;          // KK*KK
constexpr int PADC = 1;        // (KK-1)/2
constexpr float DECAY = 4.0f;
constexpr float RELT = 0.3f;
constexpr float EPSV = 1e-8f;
constexpr int H = 480;
constexpr int W = 640;
constexpr int HW = H * W;

typedef float f32x4 __attribute__((ext_vector_type(4)));   // native vector: ok for nontemporal builtins

// Tiling: each block produces a 16x64 tile; 256 threads x 4 px (float4 I/O).
constexpr int TH = 16;
constexpr int TW = 64;
constexpr int PADT = 8;              // apron: N(0,1) offsets + kernel +-1 stay within +-8 in practice
constexpr int LR = TH + 2 * PADT;    // 32 staged rows
constexpr int LC = TW + 2 * PADT;    // 80 staged cols (valid)
constexpr int LSTRIDE = LC + 1;      // 81: odd stride de-phases LDS banks across rows
constexpr int NSTAGE = LR * LC;      // 2560 = 10 * 256 exactly

// Global-path bilinear corner fetch with zero padding (rare fallback).
__device__ __forceinline__ float dsample(const float* __restrict__ img, int iy, int ix) {
    bool valid = (iy >= 0) & (iy < H) & (ix >= 0) & (ix < W);
    int iyc = min(max(iy, 0), H - 1);
    int ixc = min(max(ix, 0), W - 1);
    float v = img[iyc * W + ixc];
    return valid ? v : 0.0f;
}

// One bilinear tap for 4 consecutive pixels; returns samples in s4[0..3].
__device__ __forceinline__ void tap4(const float* __restrict__ tile,
                                     const float* __restrict__ dimg,
                                     int by0, int bx0, int r, int col,
                                     f32x4 oy, f32x4 ox, int ky, int kx,
                                     float* s4) {
#pragma unroll
    for (int j = 0; j < 4; ++j) {
        float pyt = oy[j] + (float)(r + PADT + ky);
        float pxt = ox[j] + (float)(col + j + PADT + kx);
        float y0f = floorf(pyt);
        float x0f = floorf(pxt);
        float wy = pyt - y0f;
        float wx = pxt - x0f;
        int y0 = (int)y0f;
        int x0 = (int)x0f;
        float v00, v01, v10, v11;
        if ((unsigned)y0 < (unsigned)(LR - 1) && (unsigned)x0 < (unsigned)(LC - 1)) {
            int a = y0 * LSTRIDE + x0;
            v00 = tile[a];
            v01 = tile[a + 1];
            v10 = tile[a + LSTRIDE];
            v11 = tile[a + LSTRIDE + 1];
        } else {
            int gy = y0 + by0 - PADT;
            int gx = x0 + bx0 - PADT;
            v00 = dsample(dimg, gy, gx);
            v01 = dsample(dimg, gy, gx + 1);
            v10 = dsample(dimg, gy + 1, gx);
            v11 = dsample(dimg, gy + 1, gx + 1);
        }
        float wy1 = 1.0f - wy;
        float wx1 = 1.0f - wx;
        s4[j] = v00 * wy1 * wx1 + v01 * wy1 * wx + v10 * wy * wx1 + v11 * wy * wx;
    }
}

__global__ __launch_bounds__(256, 4) void affinity_kernel(
    const float* __restrict__ depth,    // [B,1,H,W]
    const float* __restrict__ offset,   // [B,2*K2,H,W]
    float* __restrict__ out)            // [B,K2,H,W]
{
    const int bx0 = blockIdx.x * TW;
    const int by0 = blockIdx.y * TH;
    const int b   = blockIdx.z;
    const int t   = threadIdx.x;

    __shared__ float tile[LR * LSTRIDE];

    const float* __restrict__ dimg = depth + (size_t)b * HW;

    const int col = (t & 15) * 4;        // 4 consecutive x per thread (16B aligned)
    const int r   = t >> 4;              // 0..15
    const int y   = by0 + r;
    const int x   = bx0 + col;

    const size_t obase = ((size_t)b * 2 * K2) * HW + (size_t)y * W + x;
    const float* __restrict__ offp = offset + obase;

    // Issue ALL 18 offset loads up front: their HBM/L2 latency hides under the
    // LDS staging loop + barrier below (loads are LDS-independent).
    f32x4 oyv[K2], oxv[K2];
#pragma unroll
    for (int k = 0; k < K2; ++k) {
        oyv[k] = *reinterpret_cast<const f32x4*>(offp + (size_t)(2 * k) * HW);
        oxv[k] = *reinterpret_cast<const f32x4*>(offp + (size_t)(2 * k + 1) * HW);
    }

    // Stage depth apron into LDS with zero padding baked in (coalesced, exact fit).
#pragma unroll
    for (int i = 0; i < NSTAGE / 256; ++i) {
        int idx = t + i * 256;
        int rr = idx / LC;               // constant divisor
        int cc = idx - rr * LC;
        int yi = by0 - PADT + rr;
        int xi = bx0 - PADT + cc;
        float v = 0.0f;
        if ((unsigned)yi < (unsigned)H && (unsigned)xi < (unsigned)W)
            v = dimg[yi * W + xi];
        tile[rr * LSTRIDE + cc] = v;
    }
    __syncthreads();

    // Center tap first (k = 4): gives c for all channels; its own output is 1.0.
    float c4[4];
    tap4(tile, dimg, by0, bx0, r, col, oyv[4], oxv[4], 0, 0, c4);

    float thr[4], cr[4];
#pragma unroll
    for (int j = 0; j < 4; ++j) {
        thr[j] = RELT * (c4[j] + EPSV);  // diff/(c+eps)<=0.3 <=> diff<=0.3*(c+eps), c>=0
        cr[j]  = RELT * c4[j];
    }

    float* __restrict__ outp = out + ((size_t)b * K2) * HW + (size_t)y * W + x;

    // Center channel output is identically 1.0 (diff = 0 <= thr).
    {
        f32x4 ones = {1.0f, 1.0f, 1.0f, 1.0f};
        __builtin_nontemporal_store(ones, reinterpret_cast<f32x4*>(outp + (size_t)4 * HW));
    }

#pragma unroll
    for (int k = 0; k < K2; ++k) {
        if (k == 4) continue;
        float s4[4];
        tap4(tile, dimg, by0, bx0, r, col, oyv[k], oxv[k], k / KK - PADC, k % KK - PADC, s4);
        f32x4 vals;
#pragma unroll
        for (int j = 0; j < 4; ++j) {
            float diff = fabsf(s4[j] - c4[j]);
            float aff = __expf(-DECAY * (diff - cr[j]));
            vals[j] = (diff <= thr[j]) ? 1.0f : aff;
        }
        __builtin_nontemporal_store(vals, reinterpret_cast<f32x4*>(outp + (size_t)k * HW));
    }
}

extern "C" void kernel_launch(void* const* d_in, const int* in_sizes, int n_in,
                              void* d_out, int out_size, void* d_ws, size_t ws_size,
                              hipStream_t stream) {
    const float* depth = (const float*)d_in[0];
    const float* offset = (const float*)d_in[1];
    float* out = (float*)d_out;

    int B = in_sizes[0] / HW;          // depth is [B,1,H,W]
    dim3 grid(W / TW, H / TH, B);      // 10 x 30 x B
    affinity_kernel<<<grid, 256, 0, stream>>>(depth, offset, out);
}

// Round 7
// 50.144 us; speedup vs baseline: 1.3260x; 1.3260x over previous
//
#include <hip/hip_runtime.h>

// Problem constants (fixed shapes from setup_inputs)
constexpr int KK = 3;
constexpr int K2 = 9;          // KK*KK
constexpr int PADC = 1;        // (KK-1)/2
constexpr float DECAY = 4.0f;
constexpr float RELT = 0.3f;
constexpr float EPSV = 1e-8f;
constexpr int H = 480;
constexpr int W = 640;
constexpr int HW = H * W;

typedef float f32x4 __attribute__((ext_vector_type(4)));   // native vector: ok for nontemporal builtins

// Tiling: each block produces a 16x64 tile; 256 threads x 4 px (float4 I/O).
constexpr int TH = 16;
constexpr int TW = 64;
constexpr int PADT = 8;              // apron: N(0,1) offsets + kernel +-1 stay within +-8 in practice
constexpr int LR = TH + 2 * PADT;    // 32 staged rows
constexpr int LC = TW + 2 * PADT;    // 80 staged cols (valid)
constexpr int LSTRIDE = LC + 1;      // 81: odd stride de-phases LDS banks across rows
constexpr int NSTAGE = LR * LC;      // 2560 = 10 * 256 exactly

// Global-path bilinear corner fetch with zero padding (always-correct fallback).
__device__ __forceinline__ float dsample(const float* __restrict__ img, int iy, int ix) {
    bool valid = (iy >= 0) & (iy < H) & (ix >= 0) & (ix < W);
    int iyc = min(max(iy, 0), H - 1);
    int ixc = min(max(ix, 0), W - 1);
    float v = img[iyc * W + ixc];
    return valid ? v : 0.0f;
}

// One bilinear tap for 4 consecutive pixels; single fast/slow branch per tap.
__device__ __forceinline__ void tap4(const float* __restrict__ tile,
                                     const float* __restrict__ dimg,
                                     int by0, int bx0, int r, int col,
                                     f32x4 oy, f32x4 ox, int ky, int kx,
                                     float* s4) {
    int y0[4], x0[4];
    float wy[4], wx[4];
    bool fast = true;
#pragma unroll
    for (int j = 0; j < 4; ++j) {
        float pyt = oy[j] + (float)(r + PADT + ky);
        float pxt = ox[j] + (float)(col + j + PADT + kx);
        float y0f = floorf(pyt);
        float x0f = floorf(pxt);
        wy[j] = pyt - y0f;
        wx[j] = pxt - x0f;
        y0[j] = (int)y0f;
        x0[j] = (int)x0f;
        fast &= ((unsigned)y0[j] < (unsigned)(LR - 1)) & ((unsigned)x0[j] < (unsigned)(LC - 1));
    }
    if (fast) {
        // zeros for out-of-image texels are already staged in the tile
#pragma unroll
        for (int j = 0; j < 4; ++j) {
            int a = y0[j] * LSTRIDE + x0[j];
            float v00 = tile[a];
            float v01 = tile[a + 1];
            float v10 = tile[a + LSTRIDE];
            float v11 = tile[a + LSTRIDE + 1];
            float wy1 = 1.0f - wy[j];
            float wx1 = 1.0f - wx[j];
            s4[j] = v00 * wy1 * wx1 + v01 * wy1 * wx[j] + v10 * wy[j] * wx1 + v11 * wy[j] * wx[j];
        }
    } else {
        // rare: sample outside the apron -> fully general global path
#pragma unroll
        for (int j = 0; j < 4; ++j) {
            int gy = y0[j] + by0 - PADT;
            int gx = x0[j] + bx0 - PADT;
            float v00 = dsample(dimg, gy, gx);
            float v01 = dsample(dimg, gy, gx + 1);
            float v10 = dsample(dimg, gy + 1, gx);
            float v11 = dsample(dimg, gy + 1, gx + 1);
            float wy1 = 1.0f - wy[j];
            float wx1 = 1.0f - wx[j];
            s4[j] = v00 * wy1 * wx1 + v01 * wy1 * wx[j] + v10 * wy[j] * wx1 + v11 * wy[j] * wx[j];
        }
    }
}

__global__ __launch_bounds__(256) void affinity_kernel(
    const float* __restrict__ depth,    // [B,1,H,W]
    const float* __restrict__ offset,   // [B,2*K2,H,W]
    float* __restrict__ out)            // [B,K2,H,W]
{
    const int bx0 = blockIdx.x * TW;
    const int by0 = blockIdx.y * TH;
    const int b   = blockIdx.z;
    const int t   = threadIdx.x;

    __shared__ float tile[LR * LSTRIDE];

    const float* __restrict__ dimg = depth + (size_t)b * HW;

    const int col = (t & 15) * 4;        // 4 consecutive x per thread (16B aligned)
    const int r   = t >> 4;              // 0..15
    const int y   = by0 + r;
    const int x   = bx0 + col;

    const size_t obase = ((size_t)b * 2 * K2) * HW + (size_t)y * W + x;
    const float* __restrict__ offp = offset + obase;

    // Channel order: center (k=4) first so thresholds are ready before the rest.
    constexpr int ORD[K2] = {4, 0, 1, 2, 3, 5, 6, 7, 8};

    // Issue the first channel's loads before staging: latency hides under staging+barrier.
    f32x4 oyc = *reinterpret_cast<const f32x4*>(offp + (size_t)(2 * ORD[0]) * HW);
    f32x4 oxc = *reinterpret_cast<const f32x4*>(offp + (size_t)(2 * ORD[0] + 1) * HW);

    // Stage depth apron into LDS with zero padding baked in (coalesced, exact fit).
#pragma unroll
    for (int i = 0; i < NSTAGE / 256; ++i) {
        int idx = t + i * 256;
        int rr = idx / LC;               // constant divisor
        int cc = idx - rr * LC;
        int yi = by0 - PADT + rr;
        int xi = bx0 - PADT + cc;
        float v = 0.0f;
        if ((unsigned)yi < (unsigned)H && (unsigned)xi < (unsigned)W)
            v = dimg[yi * W + xi];
        tile[rr * LSTRIDE + cc] = v;
    }
    __syncthreads();

    float* __restrict__ outp = out + ((size_t)b * K2) * HW + (size_t)y * W + x;

    float c4[4], thr[4], cr[4];

    // Rolling 1-deep prefetch: issue k+1's offset loads before computing k.
#pragma unroll
    for (int i = 0; i < K2; ++i) {
        const int k = ORD[i];
        f32x4 oyn, oxn;
        if (i + 1 < K2) {
            oyn = *reinterpret_cast<const f32x4*>(offp + (size_t)(2 * ORD[i + 1]) * HW);
            oxn = *reinterpret_cast<const f32x4*>(offp + (size_t)(2 * ORD[i + 1] + 1) * HW);
        }

        float s4[4];
        tap4(tile, dimg, by0, bx0, r, col, oyc, oxc, k / KK - PADC, k % KK - PADC, s4);

        if (i == 0) {
            // center channel: defines thresholds; its own output is identically 1.0
#pragma unroll
            for (int j = 0; j < 4; ++j) {
                c4[j]  = s4[j];
                thr[j] = RELT * (s4[j] + EPSV);  // diff/(c+eps)<=0.3 <=> diff<=0.3*(c+eps), c>=0
                cr[j]  = RELT * s4[j];
            }
            f32x4 ones = {1.0f, 1.0f, 1.0f, 1.0f};
            __builtin_nontemporal_store(ones, reinterpret_cast<f32x4*>(outp + (size_t)4 * HW));
        } else {
            f32x4 vals;
#pragma unroll
            for (int j = 0; j < 4; ++j) {
                float diff = fabsf(s4[j] - c4[j]);
                float aff = __expf(-DECAY * (diff - cr[j]));
                vals[j] = (diff <= thr[j]) ? 1.0f : aff;
            }
            __builtin_nontemporal_store(vals, reinterpret_cast<f32x4*>(outp + (size_t)k * HW));
        }
        oyc = oyn;
        oxc = oxn;
    }
}

extern "C" void kernel_launch(void* const* d_in, const int* in_sizes, int n_in,
                              void* d_out, int out_size, void* d_ws, size_t ws_size,
                              hipStream_t stream) {
    const float* depth = (const float*)d_in[0];
    const float* offset = (const float*)d_in[1];
    float* out = (float*)d_out;

    int B = in_sizes[0] / HW;          // depth is [B,1,H,W]
    dim3 grid(W / TW, H / TH, B);      // 10 x 30 x B
    affinity_kernel<<<grid, 256, 0, stream>>>(depth, offset, out);
}